// Round 1
// 362.142 us; speedup vs baseline: 1.0650x; 1.0650x over previous
//
#include <hip/hip_runtime.h>
#include <math.h>
#include <stdint.h>

// LinearAttention b=8, DIM=512, L=8192, HEADS=4, DIM_HEAD=32, HIDDEN=128
// Round 4:
//  - Swapped-operand MFMA epilogue: acc = mfma(bf, af) gives D[l][m], so each
//    lane holds 4 consecutive l for a fixed m -> coalesced float4/ushort4
//    C stores (16/thread) instead of 64 scattered dword/short stores.
//  - qt kernel fused into gemm1: the y==0 block (exactly the q rows) bounces
//    its tile through the (dead) staging LDS and writes qT directly into the
//    q-slot of qkvb. W2b relocates to xb (dead after gemm1). Saves a kernel
//    launch + 32 MB of HBM traffic.
// Pipeline (qpath): misc -> xpose -> gemm<1,512,FUSE_QT>(M=384) -> ctx -> w2 -> gemm<0,128>

#define L_LEN 8192L
#define DIMC 512

typedef short bf16x8 __attribute__((ext_vector_type(8)));
typedef float f32x4 __attribute__((ext_vector_type(4)));

__device__ __forceinline__ unsigned short f2bf(float f) {
    uint32_t u = __float_as_uint(f);
    u += 0x7FFFu + ((u >> 16) & 1u);   // round-to-nearest-even
    return (unsigned short)(u >> 16);
}
__device__ __forceinline__ void unpack8(uint4 u, float* f) {
    f[0] = __uint_as_float(u.x << 16); f[1] = __uint_as_float(u.x & 0xFFFF0000u);
    f[2] = __uint_as_float(u.y << 16); f[3] = __uint_as_float(u.y & 0xFFFF0000u);
    f[4] = __uint_as_float(u.z << 16); f[5] = __uint_as_float(u.z & 0xFFFF0000u);
    f[6] = __uint_as_float(u.w << 16); f[7] = __uint_as_float(u.w & 0xFFFF0000u);
}

#define GLOAD_LDS16(g, l) __builtin_amdgcn_global_load_lds( \
    (const __attribute__((address_space(1))) uint32_t*)(g), \
    (__attribute__((address_space(3))) uint32_t*)(l), 16, 0, 0)

// ---------------- misc: cvt w_qkv (384x512) to bf16 + zero ctxU/S ----------------
__global__ __launch_bounds__(256)
void misc_kernel(const float* __restrict__ w, unsigned short* __restrict__ wb,
                 float* __restrict__ zbase)
{
    int idx = blockIdx.x * 256 + threadIdx.x;
    if (idx < 196608) wb[idx] = f2bf(w[idx]);
    else {
        int z = idx - 196608;
        if (z < 33792) zbase[z] = 0.0f;   // ctxU (32768) + S (1024), contiguous
    }
}

// ---------------- P1: transpose + fp32->bf16 ----------------
__global__ __launch_bounds__(256)
void xpose_cvt_kernel(const float* __restrict__ x, unsigned short* __restrict__ xb)
{
    const int b  = blockIdx.z;
    const int c0 = blockIdx.y * 64;
    const int l0 = blockIdx.x * 64;
    const float* xp = x + (long)b * DIMC * L_LEN;
    unsigned short* op = xb + (long)b * L_LEN * DIMC;
    __shared__ float tile[64][65];
    const int t = threadIdx.x;
    #pragma unroll
    for (int r = 0; r < 4; ++r) {
        int idx = t + 256 * r;
        int row = idx >> 4, col4 = (idx & 15) * 4;
        float4 v = *(const float4*)&xp[(long)(c0 + row) * L_LEN + l0 + col4];
        tile[row][col4 + 0] = v.x;
        tile[row][col4 + 1] = v.y;
        tile[row][col4 + 2] = v.z;
        tile[row][col4 + 3] = v.w;
    }
    __syncthreads();
    #pragma unroll
    for (int r = 0; r < 4; ++r) {
        int idx = t + 256 * r;
        int lr = idx >> 4, c4 = (idx & 15) * 4;
        ushort4 o;
        o.x = f2bf(tile[c4 + 0][lr]);
        o.y = f2bf(tile[c4 + 1][lr]);
        o.z = f2bf(tile[c4 + 2][lr]);
        o.w = f2bf(tile[c4 + 3][lr]);
        *(ushort4*)&op[(long)(l0 + lr) * DIMC + c0 + c4] = o;
    }
}

// ---------------- MFMA bf16 GEMM: C[m][l] = sum_k A[m][k]*B[l][k], BK=64 ----------------
// Swapped-operand MFMA: acc[i][j] holds D[l-row][m-col], i.e. per lane the 4
// regs are 4 consecutive l for one m -> coalesced stores.
// FUSE_QT: block m0==0 writes its tile transposed as qT[l][m] (bf16) into Cv's
// q-slot via an LDS bounce, instead of the normal row-major write.
template<int OUT_BF16, int KD, int FUSE_QT>
__global__ __launch_bounds__(256)
void mfma_gemm_kernel(const unsigned short* __restrict__ A, long aBS,
                      const unsigned short* __restrict__ B, long bBS,
                      void* __restrict__ Cv, long cBS,
                      const float* __restrict__ bias)
{
    const int b  = blockIdx.z;
    const int m0 = blockIdx.y * 128;
    const int l0 = blockIdx.x * 128;
    A += (long)b * aBS;
    B += (long)b * bBS;

    // one contiguous 32KB block: staging (Asm|Bsm) during K-loop, reused as a
    // 128x128 bf16 transpose-bounce tile in the FUSE_QT epilogue.
    __shared__ unsigned short SMEM[16384];
    unsigned short* Asm = SMEM;          // 2 sub-tiles of [128 rows][32 k]
    unsigned short* Bsm = SMEM + 8192;

    const int t = threadIdx.x;
    const int wave = t >> 6, lane = t & 63;
    const int wm = (wave & 1) * 64, wn = (wave >> 1) * 64;
    const int srow  = wave * 16 + (lane >> 2);   // staging row within 64-row half
    const int skoff = (lane & 3) * 8;            // 16B piece within 32-k sub-row
    const int fr = lane & 15, quad = lane >> 4;

    f32x4 acc[4][4] = {};

    for (int k0 = 0; k0 < KD; k0 += 64) {
        #pragma unroll
        for (int c = 0; c < 2; ++c) {
            const int kk = k0 + c * 32 + skoff;
            GLOAD_LDS16(A + (long)(m0 + srow) * KD + kk,      Asm + c * 4096 + wave * 512);
            GLOAD_LDS16(A + (long)(m0 + 64 + srow) * KD + kk, Asm + c * 4096 + 2048 + wave * 512);
            GLOAD_LDS16(B + (long)(l0 + srow) * KD + kk,      Bsm + c * 4096 + wave * 512);
            GLOAD_LDS16(B + (long)(l0 + 64 + srow) * KD + kk, Bsm + c * 4096 + 2048 + wave * 512);
        }
        __syncthreads();

        #pragma unroll
        for (int c = 0; c < 2; ++c) {
            bf16x8 af[4], bf[4];
            #pragma unroll
            for (int i = 0; i < 4; ++i)
                af[i] = *(const bf16x8*)&Asm[c * 4096 + (wm + i * 16 + fr) * 32 + quad * 8];
            #pragma unroll
            for (int j = 0; j < 4; ++j)
                bf[j] = *(const bf16x8*)&Bsm[c * 4096 + (wn + j * 16 + fr) * 32 + quad * 8];
            #pragma unroll
            for (int i = 0; i < 4; ++i)
                #pragma unroll
                for (int j = 0; j < 4; ++j)
                    acc[i][j] = __builtin_amdgcn_mfma_f32_16x16x32_bf16(bf[j], af[i], acc[i][j], 0, 0, 0);
        }
        __syncthreads();
    }
    // acc[i][j][r] = C[l0 + wn + j*16 + quad*4 + r][m0 + wm + i*16 + fr]

    if (FUSE_QT && m0 == 0) {
        // scatter tile (bf16) into SMEM as [l-local][m-local]
        #pragma unroll
        for (int i = 0; i < 4; ++i)
            #pragma unroll
            for (int j = 0; j < 4; ++j)
                #pragma unroll
                for (int r = 0; r < 4; ++r)
                    SMEM[(wn + j * 16 + quad * 4 + r) * 128 + wm + i * 16 + fr] =
                        f2bf(acc[i][j][r]);
        __syncthreads();
        // coalesced 16B stores: qT[l][m] into the q-slot of qkvb
        unsigned short* qT = (unsigned short*)Cv + (long)b * cBS;
        #pragma unroll
        for (int rep = 0; rep < 8; ++rep) {
            int idx = rep * 256 + t;             // 0..2047 chunks of 16B
            int row = idx >> 4, c8 = (idx & 15) * 8;
            *(uint4*)&qT[(long)(l0 + row) * 128 + c8] = *(const uint4*)&SMEM[row * 128 + c8];
        }
    } else {
        #pragma unroll
        for (int i = 0; i < 4; ++i) {
            const int m = m0 + wm + i * 16 + fr;
            const float bv = bias ? bias[m] : 0.0f;
            #pragma unroll
            for (int j = 0; j < 4; ++j) {
                const long lbase = l0 + wn + j * 16 + quad * 4;
                float v0 = acc[i][j][0] + bv, v1 = acc[i][j][1] + bv;
                float v2 = acc[i][j][2] + bv, v3 = acc[i][j][3] + bv;
                if (OUT_BF16) {
                    ushort4 o; o.x = f2bf(v0); o.y = f2bf(v1); o.z = f2bf(v2); o.w = f2bf(v3);
                    *(ushort4*)&((unsigned short*)Cv)[(long)b * cBS + (long)m * L_LEN + lbase] = o;
                } else {
                    float4 o; o.x = v0; o.y = v1; o.z = v2; o.w = v3;
                    *(float4*)&((float*)Cv)[(long)b * cBS + (long)m * L_LEN + lbase] = o;
                }
            }
        }
    }
}

// ---------------- ctx: unnormalized context + row-sums (no-max softmax) ----------------
// grid 2048: bid = b(3) h(2) dg(3) nc(2) esel(1). Each block: 4 d x 16 e over 2048 n.
__global__ __launch_bounds__(256)
void ctx_kernel(const unsigned short* __restrict__ kv, long batchStride, long kOff, long vOff,
                float* __restrict__ ctxU, float* __restrict__ S)
{
    const int bid  = blockIdx.x;
    const int esel = bid & 1;
    const int nc   = (bid >> 1) & 3;
    const int dg   = (bid >> 3) & 7;
    const int h    = (bid >> 6) & 3;
    const int b    = bid >> 8;
    const int d0   = dg * 4, e0 = esel * 16;
    const int t = threadIdx.x;
    const long n = (long)nc * 2048 + t * 8;

    const unsigned short* kp = kv + (long)b * batchStride + kOff + (long)(h * 32 + d0) * L_LEN + n;
    const unsigned short* vp = kv + (long)b * batchStride + vOff + (long)(h * 32 + e0) * L_LEN + n;

    float w8[4][8], s4[4];
    #pragma unroll
    for (int i = 0; i < 4; ++i) {
        uint4 u = *(const uint4*)&kp[(long)i * L_LEN];
        float f[8]; unpack8(u, f);
        float s = 0.0f;
        #pragma unroll
        for (int k = 0; k < 8; ++k) { w8[i][k] = __expf(f[k]); s += w8[i][k]; }
        s4[i] = s;
    }
    float acc[4][16];
    #pragma unroll
    for (int e = 0; e < 16; ++e) {
        uint4 u = *(const uint4*)&vp[(long)e * L_LEN];
        float g[8]; unpack8(u, g);
        #pragma unroll
        for (int i = 0; i < 4; ++i) {
            float s = 0.0f;
            #pragma unroll
            for (int k = 0; k < 8; ++k) s = fmaf(w8[i][k], g[k], s);
            acc[i][e] = s;
        }
    }

    const int wave = t >> 6, lane = t & 63;
    __shared__ float red[4][68];
    #pragma unroll
    for (int i = 0; i < 4; ++i) {
        #pragma unroll
        for (int e = 0; e < 16; ++e) {
            float v = acc[i][e];
            for (int off = 32; off; off >>= 1) v += __shfl_down(v, off, 64);
            if (lane == 0) red[wave][i * 16 + e] = v;
        }
        float sv = s4[i];
        for (int off = 32; off; off >>= 1) sv += __shfl_down(sv, off, 64);
        if (lane == 0) red[wave][64 + i] = sv;
    }
    __syncthreads();
    if (t < 68) {
        float v = red[0][t] + red[1][t] + red[2][t] + red[3][t];
        if (t < 64) {
            int i = t >> 4, e = t & 15;
            atomicAdd(&ctxU[(((long)(b * 4 + h) * 32) + d0 + i) * 32 + e0 + e], v);
        } else if (esel == 0) {
            atomicAdd(&S[b * 128 + h * 32 + d0 + (t - 64)], v);
        }
    }
}

// ---------------- w2: W2[b][o][hd] = (sum_e w_out[o][h*32+e]*ctxU[.,d,e]) / S ----------------
template<int OUT_BF16>
__global__ __launch_bounds__(256)
void w2_kernel(const float* __restrict__ w_out, const float* __restrict__ ctxU,
               const float* __restrict__ S, void* __restrict__ out)
{
    const int idx = blockIdx.x * 256 + threadIdx.x;   // < 8*512*128
    const int b = idx >> 16;
    const int rem = idx & 65535;
    const int o = rem >> 7, hd = rem & 127;
    const int h = hd >> 5, d = hd & 31;
    const float* wp = w_out + o * 128 + h * 32;
    const float* cp = ctxU + (((long)(b * 4 + h) * 32) + d) * 32;
    float s = 0.0f;
    #pragma unroll
    for (int e = 0; e < 32; e += 4) {
        float4 wv = *(const float4*)&wp[e];
        float4 cv = *(const float4*)&cp[e];
        s += wv.x * cv.x + wv.y * cv.y + wv.z * cv.z + wv.w * cv.w;
    }
    s /= S[b * 128 + hd];
    if (OUT_BF16) ((unsigned short*)out)[idx] = f2bf(s);
    else          ((float*)out)[idx] = s;
}

// ---------------- weff (fallback path): Weffb[b][o][c] bf16 = W2 @ w_q ----------------
__global__ __launch_bounds__(256)
void weff_kernel(const float* __restrict__ W2, const float* __restrict__ wq,
                 unsigned short* __restrict__ Weffb)
{
    const int b  = blockIdx.z;
    const int ot = blockIdx.y * 64;
    const int ct = blockIdx.x * 64;
    __shared__ float W2t[64][129];
    __shared__ float wqt[128][64];
    const int t = threadIdx.x;
    const float* W2b = W2 + (long)b * 512 * 128;
    #pragma unroll
    for (int r = 0; r < 8; ++r) {
        int f4 = t + 256 * r;
        int row = f4 >> 5, c4 = (f4 & 31) * 4;
        float4 v = *(const float4*)&W2b[(long)(ot + row) * 128 + c4];
        W2t[row][c4 + 0] = v.x; W2t[row][c4 + 1] = v.y;
        W2t[row][c4 + 2] = v.z; W2t[row][c4 + 3] = v.w;
    }
    #pragma unroll
    for (int r = 0; r < 8; ++r) {
        int f4 = t + 256 * r;
        int hd = f4 >> 4, c4 = (f4 & 15) * 4;
        *(float4*)&wqt[hd][c4] = *(const float4*)&wq[(long)hd * DIMC + ct + c4];
    }
    __syncthreads();
    const int oo = (t >> 4) * 4, cc = (t & 15) * 4;
    float acc[4][4] = {};
    for (int hd = 0; hd < 128; ++hd) {
        float a[4], bb[4];
        #pragma unroll
        for (int e = 0; e < 4; ++e) a[e]  = W2t[oo + e][hd];
        #pragma unroll
        for (int e = 0; e < 4; ++e) bb[e] = wqt[hd][cc + e];
        #pragma unroll
        for (int i = 0; i < 4; ++i)
            #pragma unroll
            for (int j = 0; j < 4; ++j)
                acc[i][j] = fmaf(a[i], bb[j], acc[i][j]);
    }
    #pragma unroll
    for (int i = 0; i < 4; ++i)
        #pragma unroll
        for (int j = 0; j < 4; ++j)
            Weffb[((long)b * 512 + ot + oo + i) * 512 + ct + cc + j] = f2bf(acc[i][j]);
}

extern "C" void kernel_launch(void* const* d_in, const int* in_sizes, int n_in,
                              void* d_out, int out_size, void* d_ws, size_t ws_size,
                              hipStream_t stream)
{
    const float* x     = (const float*)d_in[0];   // (8, 512, 8192)
    const float* w_qkv = (const float*)d_in[1];   // (384, 512)
    const float* w_out = (const float*)d_in[2];   // (512, 128)
    const float* b_out = (const float*)d_in[3];   // (512,)
    float* out = (float*)d_out;                   // (8, 512, 8192) f32

    char* ws = (char*)d_ws;
    unsigned short* xb = (unsigned short*)ws;     // 67,108,864 B (dead after main GEMM)

    const bool qpath = (ws_size >= 117968896UL);

    if (qpath) {
        // layout: xb[0,64M) | qkvb[64M,+48M) | tail: wb, ctxU, S  (need 117,968,896 B)
        // gemm1's m0==0 block writes qT[l][128] into the q-slot of qkvb (fused qt).
        // W2b lives in xb (dead after gemm1).
        unsigned short* qkvb = (unsigned short*)(ws + 67108864L);
        char* T = ws + 117440512L;
        unsigned short* wb = (unsigned short*)T;                 // 393,216 B
        float* ctxU = (float*)(T + 393216L);                     // 131,072 B
        float* Ssum = (float*)(T + 524288L);                     //   4,096 B
        unsigned short* W2b = xb;                                // alias (xb dead after gemm1)

        misc_kernel<<<900, 256, 0, stream>>>(w_qkv, wb, ctxU);
        xpose_cvt_kernel<<<dim3(128, 8, 8), 256, 0, stream>>>(x, xb);
        // qkv (384x8192 bf16) = wb @ xb^T ; q written transposed into q-slot
        mfma_gemm_kernel<1, 512, 1><<<dim3(64, 3, 8), 256, 0, stream>>>(
            wb, 0L, xb, L_LEN * DIMC, qkvb, 384L * L_LEN, nullptr);
        ctx_kernel<<<2048, 256, 0, stream>>>(qkvb, 384L * L_LEN, 128L * L_LEN, 256L * L_LEN,
                                             ctxU, Ssum);
        w2_kernel<1><<<2048, 256, 0, stream>>>(w_out, ctxU, Ssum, W2b);
        // out (512x8192 f32) = W2b (512x128) @ qT^T + b_out ; qT = q-slot of qkvb
        mfma_gemm_kernel<0, 128, 0><<<dim3(64, 4, 8), 256, 0, stream>>>(
            W2b, 512L * 128, qkvb, 384L * L_LEN, out, 512L * L_LEN, b_out);
    } else {
        // fallback (proven footprint): xb | kvb[64M,+32M) | tail: wb, ctxU, S (ends 101,191,680)
        unsigned short* kvb = (unsigned short*)(ws + 67108864L);
        char* T = ws + 100663296L;
        unsigned short* wb = (unsigned short*)T;
        float* ctxU = (float*)(T + 393216L);
        float* Ssum = (float*)(T + 524288L);
        unsigned short* Weffb = kvb;                             // alias, kv dead after ctx
        float* W2f = (float*)(ws + 67108864L + 4194304L);        // alias, after Weffb slot

        misc_kernel<<<900, 256, 0, stream>>>(w_qkv, wb, ctxU);
        xpose_cvt_kernel<<<dim3(128, 8, 8), 256, 0, stream>>>(x, xb);
        // kv (256x8192 bf16) = wb[128:] @ xb^T
        mfma_gemm_kernel<1, 512, 0><<<dim3(64, 2, 8), 256, 0, stream>>>(
            wb + 128 * DIMC, 0L, xb, L_LEN * DIMC, kvb, 256L * L_LEN, nullptr);
        ctx_kernel<<<2048, 256, 0, stream>>>(kvb, 256L * L_LEN, 0L, 128L * L_LEN,
                                             ctxU, Ssum);
        w2_kernel<0><<<2048, 256, 0, stream>>>(w_out, ctxU, Ssum, W2f);
        weff_kernel<<<dim3(8, 8, 8), 256, 0, stream>>>(W2f, w_qkv, Weffb);
        // out = Weffb @ xb^T + b_out
        mfma_gemm_kernel<0, 512, 0><<<dim3(64, 4, 8), 256, 0, stream>>>(
            Weffb, 512L * DIMC, xb, L_LEN * DIMC, out, 512L * L_LEN, b_out);
    }
}

// Round 2
// 355.158 us; speedup vs baseline: 1.0860x; 1.0197x over previous
//
#include <hip/hip_runtime.h>
#include <math.h>
#include <stdint.h>

// LinearAttention b=8, DIM=512, L=8192, HEADS=4, DIM_HEAD=32, HIDDEN=128
// Round 5:
//  - xpose_cvt folded into gemm1 (qpath): B operand staged directly from x
//    (f32, (b,c,l)) with in-staging f2bf + transpose into an XOR-swizzled
//    [l][c] LDS tile (write: ds_write_b32 pairs, conflict-free; read:
//    ds_read_b128 with matching chunk^=(l&7) swizzle). Saves the 201 MB
//    xpose round-trip + one launch; bit-identical numerics (same f2bf).
//  - Swapped-operand MFMA epilogue (R4): coalesced float4/ushort4 C stores.
//  - FUSE_QT (R4): gemm1's m0==0 block emits qT via LDS bounce.
// Pipeline (qpath): misc -> gemm<1,512,QT,XF32>(M=384) -> ctx -> w2 -> gemm<0,128>

#define L_LEN 8192L
#define DIMC 512

typedef short bf16x8 __attribute__((ext_vector_type(8)));
typedef float f32x4 __attribute__((ext_vector_type(4)));

__device__ __forceinline__ unsigned short f2bf(float f) {
    uint32_t u = __float_as_uint(f);
    u += 0x7FFFu + ((u >> 16) & 1u);   // round-to-nearest-even
    return (unsigned short)(u >> 16);
}
__device__ __forceinline__ void unpack8(uint4 u, float* f) {
    f[0] = __uint_as_float(u.x << 16); f[1] = __uint_as_float(u.x & 0xFFFF0000u);
    f[2] = __uint_as_float(u.y << 16); f[3] = __uint_as_float(u.y & 0xFFFF0000u);
    f[4] = __uint_as_float(u.z << 16); f[5] = __uint_as_float(u.z & 0xFFFF0000u);
    f[6] = __uint_as_float(u.w << 16); f[7] = __uint_as_float(u.w & 0xFFFF0000u);
}

#define GLOAD_LDS16(g, l) __builtin_amdgcn_global_load_lds( \
    (const __attribute__((address_space(1))) uint32_t*)(g), \
    (__attribute__((address_space(3))) uint32_t*)(l), 16, 0, 0)

// ---------------- misc: cvt w_qkv (384x512) to bf16 + zero ctxU/S ----------------
__global__ __launch_bounds__(256)
void misc_kernel(const float* __restrict__ w, unsigned short* __restrict__ wb,
                 float* __restrict__ zbase)
{
    int idx = blockIdx.x * 256 + threadIdx.x;
    if (idx < 196608) wb[idx] = f2bf(w[idx]);
    else {
        int z = idx - 196608;
        if (z < 33792) zbase[z] = 0.0f;   // ctxU (32768) + S (1024), contiguous
    }
}

// ---------------- P1 (fallback only): transpose + fp32->bf16 ----------------
__global__ __launch_bounds__(256)
void xpose_cvt_kernel(const float* __restrict__ x, unsigned short* __restrict__ xb)
{
    const int b  = blockIdx.z;
    const int c0 = blockIdx.y * 64;
    const int l0 = blockIdx.x * 64;
    const float* xp = x + (long)b * DIMC * L_LEN;
    unsigned short* op = xb + (long)b * L_LEN * DIMC;
    __shared__ float tile[64][65];
    const int t = threadIdx.x;
    #pragma unroll
    for (int r = 0; r < 4; ++r) {
        int idx = t + 256 * r;
        int row = idx >> 4, col4 = (idx & 15) * 4;
        float4 v = *(const float4*)&xp[(long)(c0 + row) * L_LEN + l0 + col4];
        tile[row][col4 + 0] = v.x;
        tile[row][col4 + 1] = v.y;
        tile[row][col4 + 2] = v.z;
        tile[row][col4 + 3] = v.w;
    }
    __syncthreads();
    #pragma unroll
    for (int r = 0; r < 4; ++r) {
        int idx = t + 256 * r;
        int lr = idx >> 4, c4 = (idx & 15) * 4;
        ushort4 o;
        o.x = f2bf(tile[c4 + 0][lr]);
        o.y = f2bf(tile[c4 + 1][lr]);
        o.z = f2bf(tile[c4 + 2][lr]);
        o.w = f2bf(tile[c4 + 3][lr]);
        *(ushort4*)&op[(long)(l0 + lr) * DIMC + c0 + c4] = o;
    }
}

// ---------------- MFMA bf16 GEMM: C[m][l] = sum_k A[m][k]*B[l][k], BK=64 ----------------
// BXF32=0: B is bf16 [l][KD] (k contiguous), staged via global_load_lds.
// BXF32=1: B is f32 x (b,c,l) with row stride L_LEN; staging does the
//   f2bf + transpose into an XOR-swizzled [128 l][64 c] bf16 LDS tile.
// acc = mfma(bf, af): acc[i][j] holds D[l-row][m-col] -> coalesced stores.
// FUSE_QT: block m0==0 writes its tile transposed as qT[l][m] into Cv's q-slot.
template<int OUT_BF16, int KD, int FUSE_QT, int BXF32>
__global__ __launch_bounds__(256)
void mfma_gemm_kernel(const unsigned short* __restrict__ A, long aBS,
                      const void* __restrict__ Bv, long bBS,
                      void* __restrict__ Cv, long cBS,
                      const float* __restrict__ bias)
{
    const int b  = blockIdx.z;
    const int m0 = blockIdx.y * 128;
    const int l0 = blockIdx.x * 128;
    A += (long)b * aBS;

    // 32KB: Asm = 2 sub-tiles [128 m][32 k]; Bsm = [128 l][64 c] (BXF32) or
    // 2 sub-tiles [128 l][32 k] (bf16 path). Reused as 128x128 bounce (FUSE_QT).
    __shared__ unsigned short SMEM[16384];
    unsigned short* Asm = SMEM;
    unsigned short* Bsm = SMEM + 8192;

    const int t = threadIdx.x;
    const int wave = t >> 6, lane = t & 63;
    const int wm = (wave & 1) * 64, wn = (wave >> 1) * 64;
    const int srow  = wave * 16 + (lane >> 2);   // staging row within 64-row half
    const int skoff = (lane & 3) * 8;            // 16B piece within 32-k sub-row
    const int fr = lane & 15, quad = lane >> 4;
    // BXF32 staging coords: c-pair p (32), l-chunk lc (8 x 16)
    const int p  = t & 31;
    const int lc = (t >> 5) * 16;

    f32x4 acc[4][4] = {};

    for (int k0 = 0; k0 < KD; k0 += 64) {
        if (BXF32) {
            // A: async global->LDS (2 c-subtiles x 2 row-halves)
            #pragma unroll
            for (int c = 0; c < 2; ++c) {
                const int kk = k0 + c * 32 + skoff;
                GLOAD_LDS16(A + (long)(m0 + srow) * KD + kk,      Asm + c * 4096 + wave * 512);
                GLOAD_LDS16(A + (long)(m0 + 64 + srow) * KD + kk, Asm + c * 4096 + 2048 + wave * 512);
            }
            // B: x rows c=k0+2p, k0+2p+1 ; floats l0+lc .. +15
            const float* X = (const float*)Bv + (long)b * bBS;
            const float* r0 = X + (long)(k0 + 2 * p) * L_LEN + l0 + lc;
            const float* r1 = r0 + L_LEN;
            float ev[16], ov[16];
            *(float4*)&ev[0]  = *(const float4*)&r0[0];
            *(float4*)&ev[4]  = *(const float4*)&r0[4];
            *(float4*)&ev[8]  = *(const float4*)&r0[8];
            *(float4*)&ev[12] = *(const float4*)&r0[12];
            *(float4*)&ov[0]  = *(const float4*)&r1[0];
            *(float4*)&ov[4]  = *(const float4*)&r1[4];
            *(float4*)&ov[8]  = *(const float4*)&r1[8];
            *(float4*)&ov[12] = *(const float4*)&r1[12];
            uint32_t* Bw = (uint32_t*)Bsm;
            #pragma unroll
            for (int j = 0; j < 16; ++j) {
                uint32_t pk = (uint32_t)f2bf(ev[j]) | ((uint32_t)f2bf(ov[j]) << 16);
                int l = lc + j;
                Bw[l * 32 + (p ^ ((l & 7) << 2))] = pk;   // byte = l*128 + 4p ^ ((l&7)<<4)
            }
        } else {
            const unsigned short* B = (const unsigned short*)Bv + (long)b * bBS;
            #pragma unroll
            for (int c = 0; c < 2; ++c) {
                const int kk = k0 + c * 32 + skoff;
                GLOAD_LDS16(A + (long)(m0 + srow) * KD + kk,      Asm + c * 4096 + wave * 512);
                GLOAD_LDS16(A + (long)(m0 + 64 + srow) * KD + kk, Asm + c * 4096 + 2048 + wave * 512);
                GLOAD_LDS16(B + (long)(l0 + srow) * KD + kk,      Bsm + c * 4096 + wave * 512);
                GLOAD_LDS16(B + (long)(l0 + 64 + srow) * KD + kk, Bsm + c * 4096 + 2048 + wave * 512);
            }
        }
        __syncthreads();

        #pragma unroll
        for (int cc = 0; cc < 2; ++cc) {
            bf16x8 af[4], bf[4];
            #pragma unroll
            for (int i = 0; i < 4; ++i)
                af[i] = *(const bf16x8*)&Asm[cc * 4096 + (wm + i * 16 + fr) * 32 + quad * 8];
            #pragma unroll
            for (int j = 0; j < 4; ++j) {
                if (BXF32)
                    bf[j] = *(const bf16x8*)&Bsm[(wn + j * 16 + fr) * 64 +
                                                 (((cc * 4 + quad) ^ (fr & 7)) << 3)];
                else
                    bf[j] = *(const bf16x8*)&Bsm[cc * 4096 + (wn + j * 16 + fr) * 32 + quad * 8];
            }
            #pragma unroll
            for (int i = 0; i < 4; ++i)
                #pragma unroll
                for (int j = 0; j < 4; ++j)
                    acc[i][j] = __builtin_amdgcn_mfma_f32_16x16x32_bf16(bf[j], af[i], acc[i][j], 0, 0, 0);
        }
        __syncthreads();
    }
    // acc[i][j][r] = C[l0 + wn + j*16 + quad*4 + r][m0 + wm + i*16 + fr]

    if (FUSE_QT && m0 == 0) {
        // scatter tile (bf16) into SMEM as [l-local][m-local]
        #pragma unroll
        for (int i = 0; i < 4; ++i)
            #pragma unroll
            for (int j = 0; j < 4; ++j)
                #pragma unroll
                for (int r = 0; r < 4; ++r)
                    SMEM[(wn + j * 16 + quad * 4 + r) * 128 + wm + i * 16 + fr] =
                        f2bf(acc[i][j][r]);
        __syncthreads();
        // coalesced 16B stores: qT[l][m] into the q-slot of qkvb
        unsigned short* qT = (unsigned short*)Cv + (long)b * cBS;
        #pragma unroll
        for (int rep = 0; rep < 8; ++rep) {
            int idx = rep * 256 + t;             // 0..2047 chunks of 16B
            int row = idx >> 4, c8 = (idx & 15) * 8;
            *(uint4*)&qT[(long)(l0 + row) * 128 + c8] = *(const uint4*)&SMEM[row * 128 + c8];
        }
    } else {
        #pragma unroll
        for (int i = 0; i < 4; ++i) {
            const int m = m0 + wm + i * 16 + fr;
            const float bv = bias ? bias[m] : 0.0f;
            #pragma unroll
            for (int j = 0; j < 4; ++j) {
                const long lbase = l0 + wn + j * 16 + quad * 4;
                float v0 = acc[i][j][0] + bv, v1 = acc[i][j][1] + bv;
                float v2 = acc[i][j][2] + bv, v3 = acc[i][j][3] + bv;
                if (OUT_BF16) {
                    ushort4 o; o.x = f2bf(v0); o.y = f2bf(v1); o.z = f2bf(v2); o.w = f2bf(v3);
                    *(ushort4*)&((unsigned short*)Cv)[(long)b * cBS + (long)m * L_LEN + lbase] = o;
                } else {
                    float4 o; o.x = v0; o.y = v1; o.z = v2; o.w = v3;
                    *(float4*)&((float*)Cv)[(long)b * cBS + (long)m * L_LEN + lbase] = o;
                }
            }
        }
    }
}

// ---------------- ctx: unnormalized context + row-sums (no-max softmax) ----------------
// grid 2048: bid = b(3) h(2) dg(3) nc(2) esel(1). Each block: 4 d x 16 e over 2048 n.
__global__ __launch_bounds__(256)
void ctx_kernel(const unsigned short* __restrict__ kv, long batchStride, long kOff, long vOff,
                float* __restrict__ ctxU, float* __restrict__ S)
{
    const int bid  = blockIdx.x;
    const int esel = bid & 1;
    const int nc   = (bid >> 1) & 3;
    const int dg   = (bid >> 3) & 7;
    const int h    = (bid >> 6) & 3;
    const int b    = bid >> 8;
    const int d0   = dg * 4, e0 = esel * 16;
    const int t = threadIdx.x;
    const long n = (long)nc * 2048 + t * 8;

    const unsigned short* kp = kv + (long)b * batchStride + kOff + (long)(h * 32 + d0) * L_LEN + n;
    const unsigned short* vp = kv + (long)b * batchStride + vOff + (long)(h * 32 + e0) * L_LEN + n;

    float w8[4][8], s4[4];
    #pragma unroll
    for (int i = 0; i < 4; ++i) {
        uint4 u = *(const uint4*)&kp[(long)i * L_LEN];
        float f[8]; unpack8(u, f);
        float s = 0.0f;
        #pragma unroll
        for (int k = 0; k < 8; ++k) { w8[i][k] = __expf(f[k]); s += w8[i][k]; }
        s4[i] = s;
    }
    float acc[4][16];
    #pragma unroll
    for (int e = 0; e < 16; ++e) {
        uint4 u = *(const uint4*)&vp[(long)e * L_LEN];
        float g[8]; unpack8(u, g);
        #pragma unroll
        for (int i = 0; i < 4; ++i) {
            float s = 0.0f;
            #pragma unroll
            for (int k = 0; k < 8; ++k) s = fmaf(w8[i][k], g[k], s);
            acc[i][e] = s;
        }
    }

    const int wave = t >> 6, lane = t & 63;
    __shared__ float red[4][68];
    #pragma unroll
    for (int i = 0; i < 4; ++i) {
        #pragma unroll
        for (int e = 0; e < 16; ++e) {
            float v = acc[i][e];
            for (int off = 32; off; off >>= 1) v += __shfl_down(v, off, 64);
            if (lane == 0) red[wave][i * 16 + e] = v;
        }
        float sv = s4[i];
        for (int off = 32; off; off >>= 1) sv += __shfl_down(sv, off, 64);
        if (lane == 0) red[wave][64 + i] = sv;
    }
    __syncthreads();
    if (t < 68) {
        float v = red[0][t] + red[1][t] + red[2][t] + red[3][t];
        if (t < 64) {
            int i = t >> 4, e = t & 15;
            atomicAdd(&ctxU[(((long)(b * 4 + h) * 32) + d0 + i) * 32 + e0 + e], v);
        } else if (esel == 0) {
            atomicAdd(&S[b * 128 + h * 32 + d0 + (t - 64)], v);
        }
    }
}

// ---------------- w2: W2[b][o][hd] = (sum_e w_out[o][h*32+e]*ctxU[.,d,e]) / S ----------------
template<int OUT_BF16>
__global__ __launch_bounds__(256)
void w2_kernel(const float* __restrict__ w_out, const float* __restrict__ ctxU,
               const float* __restrict__ S, void* __restrict__ out)
{
    const int idx = blockIdx.x * 256 + threadIdx.x;   // < 8*512*128
    const int b = idx >> 16;
    const int rem = idx & 65535;
    const int o = rem >> 7, hd = rem & 127;
    const int h = hd >> 5, d = hd & 31;
    const float* wp = w_out + o * 128 + h * 32;
    const float* cp = ctxU + (((long)(b * 4 + h) * 32) + d) * 32;
    float s = 0.0f;
    #pragma unroll
    for (int e = 0; e < 32; e += 4) {
        float4 wv = *(const float4*)&wp[e];
        float4 cv = *(const float4*)&cp[e];
        s += wv.x * cv.x + wv.y * cv.y + wv.z * cv.z + wv.w * cv.w;
    }
    s /= S[b * 128 + hd];
    if (OUT_BF16) ((unsigned short*)out)[idx] = f2bf(s);
    else          ((float*)out)[idx] = s;
}

// ---------------- weff (fallback path): Weffb[b][o][c] bf16 = W2 @ w_q ----------------
__global__ __launch_bounds__(256)
void weff_kernel(const float* __restrict__ W2, const float* __restrict__ wq,
                 unsigned short* __restrict__ Weffb)
{
    const int b  = blockIdx.z;
    const int ot = blockIdx.y * 64;
    const int ct = blockIdx.x * 64;
    __shared__ float W2t[64][129];
    __shared__ float wqt[128][64];
    const int t = threadIdx.x;
    const float* W2b = W2 + (long)b * 512 * 128;
    #pragma unroll
    for (int r = 0; r < 8; ++r) {
        int f4 = t + 256 * r;
        int row = f4 >> 5, c4 = (f4 & 31) * 4;
        float4 v = *(const float4*)&W2b[(long)(ot + row) * 128 + c4];
        W2t[row][c4 + 0] = v.x; W2t[row][c4 + 1] = v.y;
        W2t[row][c4 + 2] = v.z; W2t[row][c4 + 3] = v.w;
    }
    #pragma unroll
    for (int r = 0; r < 8; ++r) {
        int f4 = t + 256 * r;
        int hd = f4 >> 4, c4 = (f4 & 15) * 4;
        *(float4*)&wqt[hd][c4] = *(const float4*)&wq[(long)hd * DIMC + ct + c4];
    }
    __syncthreads();
    const int oo = (t >> 4) * 4, cc = (t & 15) * 4;
    float acc[4][4] = {};
    for (int hd = 0; hd < 128; ++hd) {
        float a[4], bb[4];
        #pragma unroll
        for (int e = 0; e < 4; ++e) a[e]  = W2t[oo + e][hd];
        #pragma unroll
        for (int e = 0; e < 4; ++e) bb[e] = wqt[hd][cc + e];
        #pragma unroll
        for (int i = 0; i < 4; ++i)
            #pragma unroll
            for (int j = 0; j < 4; ++j)
                acc[i][j] = fmaf(a[i], bb[j], acc[i][j]);
    }
    #pragma unroll
    for (int i = 0; i < 4; ++i)
        #pragma unroll
        for (int j = 0; j < 4; ++j)
            Weffb[((long)b * 512 + ot + oo + i) * 512 + ct + cc + j] = f2bf(acc[i][j]);
}

extern "C" void kernel_launch(void* const* d_in, const int* in_sizes, int n_in,
                              void* d_out, int out_size, void* d_ws, size_t ws_size,
                              hipStream_t stream)
{
    const float* x     = (const float*)d_in[0];   // (8, 512, 8192)
    const float* w_qkv = (const float*)d_in[1];   // (384, 512)
    const float* w_out = (const float*)d_in[2];   // (512, 128)
    const float* b_out = (const float*)d_in[3];   // (512,)
    float* out = (float*)d_out;                   // (8, 512, 8192) f32

    char* ws = (char*)d_ws;

    const bool qpath = (ws_size >= 117968896UL);

    if (qpath) {
        // layout: W2b[0,+1M) | qkvb[64M,+48M) | tail: wb, ctxU, S
        // gemm1 reads x directly (fused transpose); m0==0 block writes qT[l][128]
        // into the q-slot of qkvb.
        unsigned short* qkvb = (unsigned short*)(ws + 67108864L);
        char* T = ws + 117440512L;
        unsigned short* wb = (unsigned short*)T;                 // 393,216 B
        float* ctxU = (float*)(T + 393216L);                     // 131,072 B
        float* Ssum = (float*)(T + 524288L);                     //   4,096 B
        unsigned short* W2b = (unsigned short*)ws;               // front of ws (free in qpath)

        misc_kernel<<<900, 256, 0, stream>>>(w_qkv, wb, ctxU);
        // qkv (384x8192 bf16) = wb @ x^T  (transpose fused into staging)
        mfma_gemm_kernel<1, 512, 1, 1><<<dim3(64, 3, 8), 256, 0, stream>>>(
            wb, 0L, x, 512L * L_LEN, qkvb, 384L * L_LEN, nullptr);
        ctx_kernel<<<2048, 256, 0, stream>>>(qkvb, 384L * L_LEN, 128L * L_LEN, 256L * L_LEN,
                                             ctxU, Ssum);
        w2_kernel<1><<<2048, 256, 0, stream>>>(w_out, ctxU, Ssum, W2b);
        // out (512x8192 f32) = W2b (512x128) @ qT^T + b_out ; qT = q-slot of qkvb
        mfma_gemm_kernel<0, 128, 0, 0><<<dim3(64, 4, 8), 256, 0, stream>>>(
            W2b, 512L * 128, qkvb, 384L * L_LEN, out, 512L * L_LEN, b_out);
    } else {
        // fallback (proven footprint): xb | kvb[64M,+32M) | tail: wb, ctxU, S (ends 101,191,680)
        unsigned short* xb = (unsigned short*)ws;
        unsigned short* kvb = (unsigned short*)(ws + 67108864L);
        char* T = ws + 100663296L;
        unsigned short* wb = (unsigned short*)T;
        float* ctxU = (float*)(T + 393216L);
        float* Ssum = (float*)(T + 524288L);
        unsigned short* Weffb = kvb;                             // alias, kv dead after ctx
        float* W2f = (float*)(ws + 67108864L + 4194304L);        // alias, after Weffb slot

        misc_kernel<<<900, 256, 0, stream>>>(w_qkv, wb, ctxU);
        xpose_cvt_kernel<<<dim3(128, 8, 8), 256, 0, stream>>>(x, xb);
        // kv (256x8192 bf16) = wb[128:] @ xb^T
        mfma_gemm_kernel<1, 512, 0, 0><<<dim3(64, 2, 8), 256, 0, stream>>>(
            wb + 128 * DIMC, 0L, xb, L_LEN * DIMC, kvb, 256L * L_LEN, nullptr);
        ctx_kernel<<<2048, 256, 0, stream>>>(kvb, 256L * L_LEN, 0L, 128L * L_LEN,
                                             ctxU, Ssum);
        w2_kernel<0><<<2048, 256, 0, stream>>>(w_out, ctxU, Ssum, W2f);
        weff_kernel<<<dim3(8, 8, 8), 256, 0, stream>>>(W2f, w_qkv, Weffb);
        // out = Weffb @ xb^T + b_out
        mfma_gemm_kernel<0, 512, 0, 0><<<dim3(64, 4, 8), 256, 0, stream>>>(
            Weffb, 512L * DIMC, xb, L_LEN * DIMC, out, 512L * L_LEN, b_out);
    }
}